// Round 3
// baseline (233.542 us; speedup 1.0000x reference)
//
#include <hip/hip_runtime.h>
#include <climits>
#include <cstdint>

// ---------------- problem constants (mirror reference) ----------------
constexpr int kB  = 64;
constexpr int kG0 = 19, kG1 = 38, kG2 = 76;
constexpr int kN0 = 3 * kG0 * kG0;   // 1083
constexpr int kN1 = 3 * kG1 * kG1;   // 4332
constexpr int kN2 = 3 * kG2 * kG2;   // 17328
constexpr int kN  = kN0 + kN1 + kN2; // 22743
constexpr int kM  = 256;             // M_CAND
constexpr int kTopK = 8;
constexpr float kNEG = -1e9f;
constexpr int kHB = 4096;            // 12-bit score-histogram bins

// per-image tiles of 256 cells per level: ceil(1083/256)=5, ceil(4332/256)=17, ceil(17328/256)=68
constexpr int kT0 = 5, kT1 = 17, kT2 = 68;
constexpr int kTilesPerImg = kT0 + kT1 + kT2;  // 90
constexpr int kGridScore = kB * kTilesPerImg;  // 5760: ONE tile per block (occupancy > pipelining)

__constant__ float c_anchors[3][3][2] = {
    {{116.f, 90.f}, {156.f, 198.f}, {373.f, 326.f}},
    {{30.f, 61.f},  {62.f, 45.f},   {59.f, 119.f}},
    {{10.f, 13.f},  {16.f, 30.f},   {33.f, 23.f}},
};

typedef float f4_t __attribute__((ext_vector_type(4)));

// fast transcendentals: v_exp_f32 + v_rcp_f32 (~2-4 ULP; thresholds have huge slack)
__device__ __forceinline__ float fexpf(float x) { return __expf(x); }
__device__ __forceinline__ float frcpf(float x) { return __builtin_amdgcn_rcpf(x); }
__device__ __forceinline__ float fsigm(float x) { return frcpf(1.0f + __expf(-x)); }

// non-temporal loads (no cache allocation -> doesn't evict the harness's dirty
// poison lines from L3; still HITS L3/L2 when the line is already resident)
__device__ __forceinline__ float2 nt_load_f2(const float2* p) {
  unsigned long long v = __builtin_nontemporal_load((const unsigned long long*)p);
  union { unsigned long long u; float2 f; } c; c.u = v; return c.f;
}
__device__ __forceinline__ f4_t nt_load_f4(const f4_t* p) {
  return __builtin_nontemporal_load(p);
}

// order-preserving float->uint key (ascending). NEG maps below every score>=0.
// Valid (gate-passing) scores are > 0 -> key always has the top bit set.
__device__ __forceinline__ unsigned score_to_key(float s) {
  unsigned fb = __float_as_uint(s);
  unsigned m = (fb & 0x80000000u) ? 0xFFFFFFFFu : 0x80000000u;
  return fb ^ m;
}
__device__ __forceinline__ float key_to_score(unsigned k) {
  unsigned fb = (k & 0x80000000u) ? (k ^ 0x80000000u) : ~k;
  return __uint_as_float(fb);
}

// flat candidate index n -> cell pointer + (level, anchor, row i, col j, stride)
__device__ __forceinline__ const float* cell_ptr(
    const float* p0, const float* p1, const float* p2, int b, int n,
    int& lvl, int& a, int& gi, int& gj, float& stride) {
  const float* src; int G, m;
  if (n < kN0)            { src = p0; G = kG0; lvl = 0; m = n;             stride = 32.f; }
  else if (n < kN0 + kN1) { src = p1; G = kG1; lvl = 1; m = n - kN0;       stride = 16.f; }
  else                    { src = p2; G = kG2; lvl = 2; m = n - kN0 - kN1; stride = 8.f; }
  int gg = G * G;
  a = m / gg;
  int r = m - a * gg;
  gi = r / G;
  gj = r - gi * G;
  return src + (size_t)((((b * 3 + a) * G + gi) * G + gj)) * 26;
}

// ---------------- wave (64-lane) helpers ----------------
__device__ __forceinline__ void waveArgmax(float& v, int& i) {
  #pragma unroll
  for (int off = 1; off < 64; off <<= 1) {
    float ov = __shfl_xor(v, off);
    int oi = __shfl_xor(i, off);
    if (ov > v || (ov == v && oi < i)) { v = ov; i = oi; }
  }
}
__device__ __forceinline__ float waveMax(float v) {
  #pragma unroll
  for (int off = 1; off < 64; off <<= 1) v = fmaxf(v, __shfl_xor(v, off));
  return v;
}
__device__ __forceinline__ float sel4f(const float a[4], int q) {
  float r = a[0];
  r = (q == 1) ? a[1] : r;
  r = (q == 2) ? a[2] : r;
  r = (q == 3) ? a[3] : r;
  return r;
}
__device__ __forceinline__ int sel4i(const int a[4], int q) {
  int r = a[0];
  r = (q == 1) ? a[1] : r;
  r = (q == 2) ? a[2] : r;
  r = (q == 3) ? a[3] : r;
  return r;
}

// ---------------- kernel 1: tile score -> per-tile compacted candidate list -----------
// Single 26 KB LDS buffer -> 6 blocks/CU (24 waves, 75% occupancy; round-2 win).
// Staging: NT dwordx4 (16 B/lane) where the tile base is 16B-aligned (94.5% of bytes),
// NT float2 fallback otherwise.
// NEW: only ~16.6% of cells pass the gates, so instead of a dense 22743-key row we emit
// a ballot-compacted (key, index) list per tile + a count. Deterministic (index-ordered),
// no global atomics, no memset. Writes drop 5.8 MB -> ~1.9 MB and select's global
// sweeps disappear.
__global__ __launch_bounds__(256) void score_kernel(
    const float* __restrict__ p0, const float* __restrict__ p1, const float* __restrict__ p2,
    uint2* __restrict__ list, int* __restrict__ tcnt)
{
  __shared__ float lds[256 * 26];   // 26624 B
  __shared__ int wcnt[4];

  int t = threadIdx.x;
  int tileId = (int)blockIdx.x;
  int b = tileId / kTilesPerImg;
  int r = tileId - b * kTilesPerImg;
  const float* slab; int NL, lvlOff, tile;
  if (r < kT0)            { slab = p0; NL = kN0; lvlOff = 0;         tile = r; }
  else if (r < kT0 + kT1) { slab = p1; NL = kN1; lvlOff = kN0;       tile = r - kT0; }
  else                    { slab = p2; NL = kN2; lvlOff = kN0 + kN1; tile = r - kT0 - kT1; }
  int cellBase = tile * 256;
  int nc = min(256, NL - cellBase);
  const float* g = slab + ((size_t)b * NL + cellBase) * 26;
  int nf = nc * 26;

  if ((((uintptr_t)g) & 15) == 0) {
    int n4 = nf >> 2;
    f4_t* d4 = (f4_t*)lds;
    #pragma unroll
    for (int k = 0; k < 7; ++k) {
      int i = t + k * 256;
      if (i < n4) d4[i] = nt_load_f4((const f4_t*)g + i);
    }
    if ((nf & 3) && t == 0) {         // 2-dword tail (odd cell-count tiles)
      ((float2*)lds)[n4 << 1] = nt_load_f2((const float2*)g + (n4 << 1));
    }
  } else {
    int n2 = nf >> 1;                 // nf always even
    float2* d2 = (float2*)lds;
    #pragma unroll
    for (int k = 0; k < 13; ++k) {
      int i = t + k * 256;
      if (i < n2) d2[i] = nt_load_f2((const float2*)g + i);
    }
  }
  __syncthreads();

  bool valid = false;
  unsigned key = 0;
  if (t < nc) {
    const float2* c2 = (const float2*)&lds[t * 26];  // stride-26: 2-way bank alias (free)
    float2 ol = c2[2];                // channels 4,5
    float obj = fsigm(ol.x);
    float loc = fsigm(ol.y);
    float tch[20];
    #pragma unroll
    for (int q = 0; q < 10; ++q) { float2 v = c2[3 + q]; tch[2*q] = v.x; tch[2*q+1] = v.y; }
    float lm = tch[0];
    #pragma unroll
    for (int c = 1; c < 20; ++c) lm = fmaxf(lm, tch[c]);
    float se = 0.f;
    #pragma unroll
    for (int c = 0; c < 20; ++c) se += fexpf(tch[c] - lm);
    float cls_conf = frcpf(se);       // max of softmax == exp(0)/sum
    float conf = obj * cls_conf;
    valid = (obj >= 0.6f && loc >= 0.5f && conf >= 0.05f);
    if (valid) key = score_to_key(sqrtf(conf) * sqrtf(loc));  // (obj*cc)^.5 * loc^.5
  }

  // ballot compaction: intra-wave rank via popcount, inter-wave prefix via LDS
  unsigned long long m = __ballot(valid);
  int lane = t & 63, w = t >> 6;
  if (lane == 0) wcnt[w] = (int)__popcll(m);
  __syncthreads();
  int base = 0;
  #pragma unroll
  for (int q = 0; q < 4; ++q) if (q < w) base += wcnt[q];
  int off = base + (int)__popcll(m & ((1ull << lane) - 1ull));
  if (valid) {
    uint2 e; e.x = key; e.y = (unsigned)(lvlOff + cellBase + t);
    list[(size_t)tileId * 256 + off] = e;   // contiguous per tile -> semi-coalesced
  }
  if (t == 0) tcnt[tileId] = wcnt[0] + wcnt[1] + wcnt[2] + wcnt[3];
}

// ---------------- parallel threshold-bin finder ----------------
// Largest bin B with suffix_count(B) >= needed; cumAbove = count strictly above B; total = all.
// All 512 threads participate uniformly.
__device__ __forceinline__ void findThresholdBin(
    const int* hist, int NB, int needed,
    int& outB, int& outCumAbove, int& outTotal,
    int* shWave, int* shOut)
{
  int tid = threadIdx.x, lane = tid & 63, w = tid >> 6;
  if (tid == 0) { shOut[0] = -1; shOut[1] = 0; }
  int ipt = (NB + 511) / 512;
  int base = tid * ipt;
  int csum = 0;
  for (int i = 0; i < ipt; ++i) { int bn = base + i; if (bn < NB) csum += hist[bn]; }
  // inclusive suffix scan within wave (lane l gets sum over lanes >= l)
  int v = csum;
  #pragma unroll
  for (int off = 1; off < 64; off <<= 1) {
    int tv = __shfl_down(v, off);
    if (lane + off < 64) v += tv;
  }
  if (lane == 0) shWave[w] = v;   // wave total
  __syncthreads();
  int above = 0, total = 0;
  #pragma unroll
  for (int q = 0; q < 8; ++q) {
    int wt = shWave[q];
    total += wt;
    if (q > w) above += wt;
  }
  int S = v + above;              // suffix count including own chunk
  if (S >= needed && S - csum < needed) {   // exactly one thread's chunk crosses
    int running = S - csum;
    for (int i = ipt - 1; i >= 0; --i) {
      int bn = base + i; if (bn >= NB) continue;
      int c = hist[bn];
      if (running + c >= needed) { shOut[0] = bn; shOut[1] = running; break; }
      running += c;
    }
  }
  __syncthreads();
  outB = shOut[0]; outCumAbove = shOut[1]; outTotal = total;
  __syncthreads();
}

// ---------------- kernel 2: LDS-resident select + soft-NMS (wave 0) -------------------
// Reads only the compacted candidate list (~3.8k entries/image, ~30 KB) instead of
// sweeping the dense 91 KB key row twice. Prefix-sums 90 tile counts, gathers entries
// into LDS (binary-searched segment lookup -> independent coalesced loads), then all
// histogram/threshold/tie passes run on LDS. Global fallback for total > kCap
// (never hit on this data; ~3.8k << 6144). Candidate set + scores bit-identical.
constexpr int kCap = 6144;
__global__ __launch_bounds__(512) void select_nms_kernel(
    const uint2* __restrict__ list, const int* __restrict__ tcnt,
    const float* __restrict__ p0, const float* __restrict__ p1, const float* __restrict__ p2,
    float* __restrict__ out)
{
  int b = blockIdx.x, tid = threadIdx.x;
  const unsigned keyNEG = score_to_key(kNEG);

  __shared__ int hist[kHB];                 // 16 KB (hi-hist, then mid/lo-hist)
  __shared__ int shWave[8], shOut[2];
  __shared__ int ciL[kM];
  __shared__ unsigned ckL[kM];
  __shared__ unsigned eK[kCap];             // 24 KB: candidate keys
  __shared__ unsigned short eI[kCap];       // 12 KB: candidate indices (n < 22743 < 2^16)
  __shared__ int segOff[kTilesPerImg + 1];
  __shared__ int eqI[256];                  // exact-key tie indices (fast path)
  __shared__ int sCnt, sTie;

  // ---- per-tile counts -> prefix sums ----
  if (tid < kTilesPerImg) segOff[tid + 1] = tcnt[b * kTilesPerImg + tid];
  if (tid == 0) segOff[0] = 0;
  __syncthreads();
  if (tid == 0) { for (int s = 0; s < kTilesPerImg; ++s) segOff[s + 1] += segOff[s]; }
  __syncthreads();
  int total = segOff[kTilesPerImg];
  bool inLds = (total <= kCap);

  // entry accessor: LDS if gathered, else global via segment binary search (uniform branch)
  auto entryAt = [&](int i) -> uint2 {
    if (inLds) { uint2 e; e.x = eK[i]; e.y = eI[i]; return e; }
    int lo = 0, hi = kTilesPerImg - 1;
    while (lo < hi) { int mid = (lo + hi + 1) >> 1; if (segOff[mid] <= i) lo = mid; else hi = mid - 1; }
    return list[((size_t)b * kTilesPerImg + lo) * 256 + (i - segOff[lo])];
  };

  // ---- gather compacted list into LDS (independent loads; latency overlaps) ----
  if (inLds) {
    for (int i = tid; i < total; i += 512) {
      int lo = 0, hi = kTilesPerImg - 1;
      while (lo < hi) { int mid = (lo + hi + 1) >> 1; if (segOff[mid] <= i) lo = mid; else hi = mid - 1; }
      uint2 e = list[((size_t)b * kTilesPerImg + lo) * 256 + (i - segOff[lo])];
      eK[i] = e.x; eI[i] = (unsigned short)e.y;
    }
  }
  if (tid == 0) { sCnt = 0; sTie = 0; }
  __syncthreads();

  if (total < kM) {
    // ---- fewer than 256 valid: direct copy, pad with dummies ----
    for (int i = tid; i < total; i += 512) { uint2 e = entryAt(i); ciL[i] = (int)e.y; ckL[i] = e.x; }
    __syncthreads();
    if (tid >= total && tid < kM) { ciL[tid] = -1; ckL[tid] = keyNEG; }
    __syncthreads();
  } else {
    // ---- hi-12-bit histogram (all entries valid by construction) ----
    for (int i = tid; i < kHB; i += 512) hist[i] = 0;
    __syncthreads();
    for (int i = tid; i < total; i += 512) atomicAdd(&hist[entryAt(i).x >> 20], 1);
    __syncthreads();
    int B, cumAbove1, t1;
    findThresholdBin(hist, kHB, kM, B, cumAbove1, t1, shWave, shOut);
    unsigned uB = (unsigned)B;
    for (int i = tid; i < kHB; i += 512) hist[i] = 0;   // reuse as mid-hist
    __syncthreads();

    // ---- pass A: gather hi>B winners; hist mid bits of hi==B ----
    for (int i = tid; i < total; i += 512) {
      uint2 e = entryAt(i);
      unsigned hi = e.x >> 20;
      if (hi > uB) { int p = atomicAdd(&sCnt, 1); ciL[p] = (int)e.y; ckL[p] = e.x; }
      else if (hi == uB) atomicAdd(&hist[(e.x >> 8) & 0xFFFu], 1);
    }
    __syncthreads();
    int needed = kM - cumAbove1;   // >= 1
    int B2, cA2, t2;
    findThresholdBin(hist, kHB, needed, B2, cA2, t2, shWave, shOut);
    for (int i = tid; i < 256; i += 512) hist[i] = 0;   // reuse as lo-hist
    __syncthreads();

    // ---- pass B: gather mid>B2 within bin B; hist low bits of mid==B2 ----
    for (int i = tid; i < total; i += 512) {
      uint2 e = entryAt(i);
      if ((e.x >> 20) == uB) {
        int mid = (int)((e.x >> 8) & 0xFFFu);
        if (mid > B2) { int p = atomicAdd(&sCnt, 1); ciL[p] = (int)e.y; ckL[p] = e.x; }
        else if (mid == B2) atomicAdd(&hist[e.x & 0xFFu], 1);
      }
    }
    __syncthreads();
    int needed3 = needed - cA2;
    int B3, cA3, t3;
    findThresholdBin(hist, 256, needed3, B3, cA3, t3, shWave, shOut);

    // ---- pass C: gather lo>B3; collect exact-threshold ties ----
    for (int i = tid; i < total; i += 512) {
      uint2 e = entryAt(i);
      if ((e.x >> 20) == uB && (int)((e.x >> 8) & 0xFFFu) == B2) {
        int lo = (int)(e.x & 0xFFu);
        if (lo > B3) { int p = atomicAdd(&sCnt, 1); ciL[p] = (int)e.y; ckL[p] = e.x; }
        else if (lo == B3) { int p = atomicAdd(&sTie, 1); if (p < 256) eqI[p] = (int)e.y; }
      }
    }
    __syncthreads();
    int needed4 = needed3 - cA3;   // >= 1; slots [0, kM-needed4) now filled
    unsigned exactKey = (uB << 20) | ((unsigned)B2 << 8) | (unsigned)B3;
    int ties = sTie;
    if (ties == needed4) {
      // typical: exact-threshold key unique (or exactly fills) -> direct append
      if (tid < needed4) { ciL[kM - needed4 + tid] = eqI[tid]; ckL[kM - needed4 + tid] = exactKey; }
    } else if (tid == 0) {
      // rare: surplus exact-key ties -> smallest original indices win (reference order)
      int base0 = kM - needed4; int lastI = -1;
      for (int q = 0; q < needed4; ++q) {
        int mv = INT_MAX;
        for (int i = 0; i < total; ++i) {
          uint2 e = entryAt(i);
          if (e.x == exactKey) { int ix = (int)e.y; if (ix > lastI && ix < mv) mv = ix; }
        }
        ciL[base0 + q] = mv; ckL[base0 + q] = exactKey; lastI = mv;
      }
    }
    __syncthreads();
  }

  // ================= NMS phase: wave 0 only, 4 candidates/lane, register state =========
  if (tid >= 64) return;
  int lane = tid;

  float x1[4], y1[4], x2[4], y2[4], val[4], s[4];
  int cls[4];
  bool kept[4];

  #pragma unroll
  for (int q = 0; q < 4; ++q) {
    int slot = q * 64 + lane;
    int n = ciL[slot];
    float sc = key_to_score(ckL[slot]);  // bit-exact score from kernel 1 (kNEG for filler)
    kept[q] = false;
    x1[q] = y1[q] = x2[q] = y2[q] = 0.f;
    cls[q] = 0; val[q] = sc; s[q] = sc;
    if (n >= 0) {
      int lvl, a, gi, gj; float stride;
      const float* p = cell_ptr(p0, p1, p2, b, n, lvl, a, gi, gj, stride);
      const float2* r2 = (const float2*)p;   // rows are 104 B: even-float offsets 8B-aligned
      float2 c01 = r2[0], c23 = r2[1];
      float cx = (fsigm(c01.x) + (float)gj) * stride;
      float cy = (fsigm(c01.y) + (float)gi) * stride;
      float w = fexpf(c23.x) * c_anchors[lvl][a][0];  // (exp*anc/stride)*stride == exp*anc
      float h = fexpf(c23.y) * c_anchors[lvl][a][1];
      x1[q] = fminf(fmaxf(cx - 0.5f * w, 0.f), 608.f);
      y1[q] = fminf(fmaxf(cy - 0.5f * h, 0.f), 608.f);
      x2[q] = fminf(fmaxf(cx + 0.5f * w, 0.f), 608.f);
      y2[q] = fminf(fmaxf(cy + 0.5f * h, 0.f), 608.f);
      float lm = -3.4e38f; int mc = 0;
      #pragma unroll
      for (int j = 3; j < 13; ++j) {
        float2 v = r2[j];
        int c0 = 2 * (j - 3);
        if (v.x > lm) { lm = v.x; mc = c0; }
        if (v.y > lm) { lm = v.y; mc = c0 + 1; }
      }
      cls[q] = mc;
    }
  }

  // top-8 kept ORIGINAL scores, maintained identically (uniformly) on all lanes
  float top8[8];
  #pragma unroll
  for (int i = 0; i < 8; ++i) top8[i] = kNEG;
  int keptCount = 0;

  for (int it = 0; it < kM; ++it) {
    float bv = s[0]; int bq = 0;
    #pragma unroll
    for (int q = 1; q < 4; ++q) if (s[q] > bv) { bv = s[q]; bq = q; }
    int bi = bq * 64 + lane;
    waveArgmax(bv, bi);
    if (bv < 0.1f) break;   // all remaining reference steps are no-ops -> exact

    int wlane = bi & 63, wq = bi >> 6;
    float jx1 = __shfl(sel4f(x1, wq), wlane);
    float jy1 = __shfl(sel4f(y1, wq), wlane);
    float jx2 = __shfl(sel4f(x2, wq), wlane);
    float jy2 = __shfl(sel4f(y2, wq), wlane);
    float jval = __shfl(sel4f(val, wq), wlane);
    int   cj  = __shfl(sel4i(cls, wq), wlane);

    float a1 = (jx2 - jx1 + 1.0f) * (jy2 - jy1 + 1.0f);
    #pragma unroll
    for (int q = 0; q < 4; ++q) {
      if (cls[q] == cj) {
        float ix1 = fmaxf(jx1, x1[q]), iy1 = fmaxf(jy1, y1[q]);
        float ix2 = fminf(jx2, x2[q]), iy2 = fminf(jy2, y2[q]);
        float inter = fmaxf(ix2 - ix1 + 1.0f, 0.0f) * fmaxf(iy2 - iy1 + 1.0f, 0.0f);
        float a2 = (x2[q] - x1[q] + 1.0f) * (y2[q] - y1[q] + 1.0f);
        float iou = inter / (a1 + a2 - inter + 1e-16f);
        s[q] *= fexpf(-(iou * iou) * 2.0f);
      }
      if (bi == q * 64 + lane) { kept[q] = true; s[q] = kNEG; }  // winner slot
    }

    // early-stop bookkeeping (uniform scalar work on every lane)
    float v = jval;
    #pragma unroll
    for (int i = 0; i < 8; ++i) { float m = fmaxf(top8[i], v); v = fminf(top8[i], v); top8[i] = m; }
    ++keptCount;
    if (keptCount >= kTopK) {
      float am = kNEG;
      #pragma unroll
      for (int q = 0; q < 4; ++q) if (s[q] >= 0.1f) am = fmaxf(am, val[q]);
      am = waveMax(am);
      // no alive candidate's ORIGINAL score can beat the 8th-best kept original:
      // s is monotone non-increasing, originals fixed, kept flags never revert -> exact stop
      if (am < top8[7]) break;
    }
  }

  // keep_top_k by ORIGINAL score among kept
  float f[4];
  #pragma unroll
  for (int q = 0; q < 4; ++q) f[q] = kept[q] ? val[q] : kNEG;
  for (int k = 0; k < kTopK; ++k) {
    float bv = f[0]; int bq = 0;
    #pragma unroll
    for (int q = 1; q < 4; ++q) if (f[q] > bv) { bv = f[q]; bq = q; }
    int bi = bq * 64 + lane;
    waveArgmax(bv, bi);
    int wlane = bi & 63, wq = bi >> 6;
    if (lane == wlane) {
      float* o = out + (size_t)(b * kTopK + k) * 6;
      if (bv > kNEG * 0.5f) {
        o[0] = sel4f(x1, wq); o[1] = sel4f(y1, wq);
        o[2] = sel4f(x2, wq); o[3] = sel4f(y2, wq);
        o[4] = sel4f(val, wq); o[5] = (float)sel4i(cls, wq);
      } else {
        o[0] = 0.f; o[1] = 0.f; o[2] = 0.f; o[3] = 0.f; o[4] = 0.f; o[5] = 0.f;
      }
    }
    #pragma unroll
    for (int q = 0; q < 4; ++q) if (bi == q * 64 + lane) f[q] = kNEG;
  }
}

// ---------------- host launch ----------------
extern "C" void kernel_launch(void* const* d_in, const int* in_sizes, int n_in,
                              void* d_out, int out_size, void* d_ws, size_t ws_size,
                              hipStream_t stream) {
  const float* p0 = (const float*)d_in[0];
  const float* p1 = (const float*)d_in[1];
  const float* p2 = (const float*)d_in[2];
  float* out = (float*)d_out;

  // workspace layout:
  //   list uint2[kB*90*256]  11.80 MB  per-tile compacted (key, index) candidate pairs
  //   tcnt int[kB*90]        23 KB     per-tile candidate counts (always fully written)
  uint2* list = (uint2*)d_ws;
  int* tcnt = (int*)((char*)d_ws + (size_t)kB * kTilesPerImg * 256 * sizeof(uint2));

  score_kernel<<<kGridScore, 256, 0, stream>>>(p0, p1, p2, list, tcnt);
  select_nms_kernel<<<kB, 512, 0, stream>>>(list, tcnt, p0, p1, p2, out);
}

// Round 4
// 228.736 us; speedup vs baseline: 1.0210x; 1.0210x over previous
//
#include <hip/hip_runtime.h>
#include <climits>
#include <cstdint>

// ---------------- problem constants (mirror reference) ----------------
constexpr int kB  = 64;
constexpr int kG0 = 19, kG1 = 38, kG2 = 76;
constexpr int kN0 = 3 * kG0 * kG0;   // 1083
constexpr int kN1 = 3 * kG1 * kG1;   // 4332
constexpr int kN2 = 3 * kG2 * kG2;   // 17328
constexpr int kN  = kN0 + kN1 + kN2; // 22743
constexpr int kM  = 256;             // M_CAND
constexpr int kTopK = 8;
constexpr float kNEG = -1e9f;
constexpr int kHB = 4096;            // 12-bit score-histogram bins

// per-image tiles of 256 cells per level: ceil(1083/256)=5, ceil(4332/256)=17, ceil(17328/256)=68
constexpr int kT0 = 5, kT1 = 17, kT2 = 68;
constexpr int kTilesPerImg = kT0 + kT1 + kT2;  // 90
constexpr int kGridScore = kB * kTilesPerImg;  // 5760: ONE tile per block (occupancy > pipelining)

__constant__ float c_anchors[3][3][2] = {
    {{116.f, 90.f}, {156.f, 198.f}, {373.f, 326.f}},
    {{30.f, 61.f},  {62.f, 45.f},   {59.f, 119.f}},
    {{10.f, 13.f},  {16.f, 30.f},   {33.f, 23.f}},
};

typedef float f4_t __attribute__((ext_vector_type(4)));

// fast transcendentals: v_exp_f32 + v_rcp_f32 (~2-4 ULP; thresholds have huge slack)
__device__ __forceinline__ float fexpf(float x) { return __expf(x); }
__device__ __forceinline__ float frcpf(float x) { return __builtin_amdgcn_rcpf(x); }
__device__ __forceinline__ float fsigm(float x) { return frcpf(1.0f + __expf(-x)); }

// non-temporal loads (no cache allocation -> doesn't evict the harness's dirty
// poison lines from L3; still HITS L3/L2 when the line is already resident)
__device__ __forceinline__ float2 nt_load_f2(const float2* p) {
  unsigned long long v = __builtin_nontemporal_load((const unsigned long long*)p);
  union { unsigned long long u; float2 f; } c; c.u = v; return c.f;
}
__device__ __forceinline__ f4_t nt_load_f4(const f4_t* p) {
  return __builtin_nontemporal_load(p);
}

// order-preserving float->uint key (ascending). NEG maps below every score>=0.
// Valid (gate-passing) scores are > 0 -> key always has the top bit set.
__device__ __forceinline__ unsigned score_to_key(float s) {
  unsigned fb = __float_as_uint(s);
  unsigned m = (fb & 0x80000000u) ? 0xFFFFFFFFu : 0x80000000u;
  return fb ^ m;
}
__device__ __forceinline__ float key_to_score(unsigned k) {
  unsigned fb = (k & 0x80000000u) ? (k ^ 0x80000000u) : ~k;
  return __uint_as_float(fb);
}

// flat candidate index n -> cell pointer + (level, anchor, row i, col j, stride)
__device__ __forceinline__ const float* cell_ptr(
    const float* p0, const float* p1, const float* p2, int b, int n,
    int& lvl, int& a, int& gi, int& gj, float& stride) {
  const float* src; int G, m;
  if (n < kN0)            { src = p0; G = kG0; lvl = 0; m = n;             stride = 32.f; }
  else if (n < kN0 + kN1) { src = p1; G = kG1; lvl = 1; m = n - kN0;       stride = 16.f; }
  else                    { src = p2; G = kG2; lvl = 2; m = n - kN0 - kN1; stride = 8.f; }
  int gg = G * G;
  a = m / gg;
  int r = m - a * gg;
  gi = r / G;
  gj = r - gi * G;
  return src + (size_t)((((b * 3 + a) * G + gi) * G + gj)) * 26;
}

// ---------------- wave (64-lane) helpers ----------------
__device__ __forceinline__ void waveArgmax(float& v, int& i) {
  #pragma unroll
  for (int off = 1; off < 64; off <<= 1) {
    float ov = __shfl_xor(v, off);
    int oi = __shfl_xor(i, off);
    if (ov > v || (ov == v && oi < i)) { v = ov; i = oi; }
  }
}
__device__ __forceinline__ float waveMax(float v) {
  #pragma unroll
  for (int off = 1; off < 64; off <<= 1) v = fmaxf(v, __shfl_xor(v, off));
  return v;
}
__device__ __forceinline__ float sel4f(const float a[4], int q) {
  float r = a[0];
  r = (q == 1) ? a[1] : r;
  r = (q == 2) ? a[2] : r;
  r = (q == 3) ? a[3] : r;
  return r;
}
__device__ __forceinline__ int sel4i(const int a[4], int q) {
  int r = a[0];
  r = (q == 1) ? a[1] : r;
  r = (q == 2) ? a[2] : r;
  r = (q == 3) ? a[3] : r;
  return r;
}

// ---------------- kernel 1: tile score -> per-tile compacted candidate list -----------
// Single 26 KB LDS buffer -> 6 blocks/CU (24 waves, 75% occupancy; round-2 win).
// Staging: NT dwordx4 (16 B/lane) where the tile base is 16B-aligned (94.5% of bytes),
// NT float2 fallback otherwise.
// Only ~16.6% of cells pass the gates, so instead of a dense 22743-key row we emit a
// ballot-compacted (key, index) list per tile + a count. Deterministic (index-ordered),
// no global atomics, no memset.
__global__ __launch_bounds__(256) void score_kernel(
    const float* __restrict__ p0, const float* __restrict__ p1, const float* __restrict__ p2,
    uint2* __restrict__ list, int* __restrict__ tcnt)
{
  __shared__ float lds[256 * 26];   // 26624 B
  __shared__ int wcnt[4];

  int t = threadIdx.x;
  int tileId = (int)blockIdx.x;
  int b = tileId / kTilesPerImg;
  int r = tileId - b * kTilesPerImg;
  const float* slab; int NL, lvlOff, tile;
  if (r < kT0)            { slab = p0; NL = kN0; lvlOff = 0;         tile = r; }
  else if (r < kT0 + kT1) { slab = p1; NL = kN1; lvlOff = kN0;       tile = r - kT0; }
  else                    { slab = p2; NL = kN2; lvlOff = kN0 + kN1; tile = r - kT0 - kT1; }
  int cellBase = tile * 256;
  int nc = min(256, NL - cellBase);
  const float* g = slab + ((size_t)b * NL + cellBase) * 26;
  int nf = nc * 26;

  if ((((uintptr_t)g) & 15) == 0) {
    int n4 = nf >> 2;
    f4_t* d4 = (f4_t*)lds;
    #pragma unroll
    for (int k = 0; k < 7; ++k) {
      int i = t + k * 256;
      if (i < n4) d4[i] = nt_load_f4((const f4_t*)g + i);
    }
    if ((nf & 3) && t == 0) {         // 2-dword tail (odd cell-count tiles)
      ((float2*)lds)[n4 << 1] = nt_load_f2((const float2*)g + (n4 << 1));
    }
  } else {
    int n2 = nf >> 1;                 // nf always even
    float2* d2 = (float2*)lds;
    #pragma unroll
    for (int k = 0; k < 13; ++k) {
      int i = t + k * 256;
      if (i < n2) d2[i] = nt_load_f2((const float2*)g + i);
    }
  }
  __syncthreads();

  bool valid = false;
  unsigned key = 0;
  if (t < nc) {
    const float2* c2 = (const float2*)&lds[t * 26];  // stride-26: 2-way bank alias (free)
    float2 ol = c2[2];                // channels 4,5
    float obj = fsigm(ol.x);
    float loc = fsigm(ol.y);
    float tch[20];
    #pragma unroll
    for (int q = 0; q < 10; ++q) { float2 v = c2[3 + q]; tch[2*q] = v.x; tch[2*q+1] = v.y; }
    float lm = tch[0];
    #pragma unroll
    for (int c = 1; c < 20; ++c) lm = fmaxf(lm, tch[c]);
    float se = 0.f;
    #pragma unroll
    for (int c = 0; c < 20; ++c) se += fexpf(tch[c] - lm);
    float cls_conf = frcpf(se);       // max of softmax == exp(0)/sum
    float conf = obj * cls_conf;
    valid = (obj >= 0.6f && loc >= 0.5f && conf >= 0.05f);
    if (valid) key = score_to_key(sqrtf(conf) * sqrtf(loc));  // (obj*cc)^.5 * loc^.5
  }

  // ballot compaction: intra-wave rank via popcount, inter-wave prefix via LDS
  unsigned long long m = __ballot(valid);
  int lane = t & 63, w = t >> 6;
  if (lane == 0) wcnt[w] = (int)__popcll(m);
  __syncthreads();
  int base = 0;
  #pragma unroll
  for (int q = 0; q < 4; ++q) if (q < w) base += wcnt[q];
  int off = base + (int)__popcll(m & ((1ull << lane) - 1ull));
  if (valid) {
    uint2 e; e.x = key; e.y = (unsigned)(lvlOff + cellBase + t);
    list[(size_t)tileId * 256 + off] = e;   // contiguous per tile -> semi-coalesced
  }
  if (t == 0) tcnt[tileId] = wcnt[0] + wcnt[1] + wcnt[2] + wcnt[3];
}

// ---------------- parallel threshold-bin finder ----------------
// Largest bin B with suffix_count(B) >= needed; cumAbove = count strictly above B; total = all.
// All 512 threads participate uniformly.
__device__ __forceinline__ void findThresholdBin(
    const int* hist, int NB, int needed,
    int& outB, int& outCumAbove, int& outTotal,
    int* shWave, int* shOut)
{
  int tid = threadIdx.x, lane = tid & 63, w = tid >> 6;
  if (tid == 0) { shOut[0] = -1; shOut[1] = 0; }
  int ipt = (NB + 511) / 512;
  int base = tid * ipt;
  int csum = 0;
  for (int i = 0; i < ipt; ++i) { int bn = base + i; if (bn < NB) csum += hist[bn]; }
  // inclusive suffix scan within wave (lane l gets sum over lanes >= l)
  int v = csum;
  #pragma unroll
  for (int off = 1; off < 64; off <<= 1) {
    int tv = __shfl_down(v, off);
    if (lane + off < 64) v += tv;
  }
  if (lane == 0) shWave[w] = v;   // wave total
  __syncthreads();
  int above = 0, total = 0;
  #pragma unroll
  for (int q = 0; q < 8; ++q) {
    int wt = shWave[q];
    total += wt;
    if (q > w) above += wt;
  }
  int S = v + above;              // suffix count including own chunk
  if (S >= needed && S - csum < needed) {   // exactly one thread's chunk crosses
    int running = S - csum;
    for (int i = ipt - 1; i >= 0; --i) {
      int bn = base + i; if (bn >= NB) continue;
      int c = hist[bn];
      if (running + c >= needed) { shOut[0] = bn; shOut[1] = running; break; }
      running += c;
    }
  }
  __syncthreads();
  outB = shOut[0]; outCumAbove = shOut[1]; outTotal = total;
  __syncthreads();
}

// ---------------- kernel 2: LDS-resident select + soft-NMS (wave 0) -------------------
// Reads only the compacted candidate list (~3.8k entries/image, ~30 KB) instead of
// sweeping the dense 91 KB key row twice. Prefix-sums 90 tile counts, then a
// SEGMENT-PARALLEL copy (wave w handles tiles w, w+8, ...; lanes copy that tile's
// contiguous entries) gathers everything into LDS -- no per-element binary search
// (round-3's extra cost). All histogram/threshold/tie passes then run on LDS.
// Global fallback (binary-search accessor) only for total > kCap (never hit: ~3.8k).
// Candidate set + scores bit-identical to the dense-sweep versions.
constexpr int kCap = 6144;
__global__ __launch_bounds__(512) void select_nms_kernel(
    const uint2* __restrict__ list, const int* __restrict__ tcnt,
    const float* __restrict__ p0, const float* __restrict__ p1, const float* __restrict__ p2,
    float* __restrict__ out)
{
  int b = blockIdx.x, tid = threadIdx.x;
  const unsigned keyNEG = score_to_key(kNEG);

  __shared__ int hist[kHB];                 // 16 KB (hi-hist, then mid/lo-hist)
  __shared__ int shWave[8], shOut[2];
  __shared__ int ciL[kM];
  __shared__ unsigned ckL[kM];
  __shared__ unsigned eK[kCap];             // 24 KB: candidate keys
  __shared__ unsigned short eI[kCap];       // 12 KB: candidate indices (n < 22743 < 2^16)
  __shared__ int segOff[kTilesPerImg + 1];
  __shared__ int eqI[256];                  // exact-key tie indices (fast path)
  __shared__ int sCnt, sTie;

  // ---- per-tile counts -> prefix sums ----
  if (tid < kTilesPerImg) segOff[tid + 1] = tcnt[b * kTilesPerImg + tid];
  if (tid == 0) segOff[0] = 0;
  __syncthreads();
  if (tid == 0) { for (int s = 0; s < kTilesPerImg; ++s) segOff[s + 1] += segOff[s]; }
  __syncthreads();
  int total = segOff[kTilesPerImg];
  bool inLds = (total <= kCap);

  // entry accessor: LDS if gathered, else global via segment binary search (fallback only)
  auto entryAt = [&](int i) -> uint2 {
    if (inLds) { uint2 e; e.x = eK[i]; e.y = eI[i]; return e; }
    int lo = 0, hi = kTilesPerImg - 1;
    while (lo < hi) { int mid = (lo + hi + 1) >> 1; if (segOff[mid] <= i) lo = mid; else hi = mid - 1; }
    return list[((size_t)b * kTilesPerImg + lo) * 256 + (i - segOff[lo])];
  };

  // ---- segment-parallel gather into LDS: wave w copies tiles w, w+8, ... ----
  if (inLds) {
    int lane = tid & 63, w = tid >> 6;
    for (int s = w; s < kTilesPerImg; s += 8) {
      int o0 = segOff[s];
      int cnt = segOff[s + 1] - o0;
      const uint2* src = list + ((size_t)b * kTilesPerImg + s) * 256;
      for (int i = lane; i < cnt; i += 64) {
        uint2 e = src[i];
        eK[o0 + i] = e.x; eI[o0 + i] = (unsigned short)e.y;
      }
    }
  }
  if (tid == 0) { sCnt = 0; sTie = 0; }
  __syncthreads();

  if (total < kM) {
    // ---- fewer than 256 valid: direct copy, pad with dummies ----
    for (int i = tid; i < total; i += 512) { uint2 e = entryAt(i); ciL[i] = (int)e.y; ckL[i] = e.x; }
    __syncthreads();
    if (tid >= total && tid < kM) { ciL[tid] = -1; ckL[tid] = keyNEG; }
    __syncthreads();
  } else {
    // ---- hi-12-bit histogram (all entries valid by construction) ----
    for (int i = tid; i < kHB; i += 512) hist[i] = 0;
    __syncthreads();
    for (int i = tid; i < total; i += 512) atomicAdd(&hist[entryAt(i).x >> 20], 1);
    __syncthreads();
    int B, cumAbove1, t1;
    findThresholdBin(hist, kHB, kM, B, cumAbove1, t1, shWave, shOut);
    unsigned uB = (unsigned)B;
    for (int i = tid; i < kHB; i += 512) hist[i] = 0;   // reuse as mid-hist
    __syncthreads();

    // ---- pass A: gather hi>B winners; hist mid bits of hi==B ----
    for (int i = tid; i < total; i += 512) {
      uint2 e = entryAt(i);
      unsigned hi = e.x >> 20;
      if (hi > uB) { int p = atomicAdd(&sCnt, 1); ciL[p] = (int)e.y; ckL[p] = e.x; }
      else if (hi == uB) atomicAdd(&hist[(e.x >> 8) & 0xFFFu], 1);
    }
    __syncthreads();
    int needed = kM - cumAbove1;   // >= 1
    int B2, cA2, t2;
    findThresholdBin(hist, kHB, needed, B2, cA2, t2, shWave, shOut);
    for (int i = tid; i < 256; i += 512) hist[i] = 0;   // reuse as lo-hist
    __syncthreads();

    // ---- pass B: gather mid>B2 within bin B; hist low bits of mid==B2 ----
    for (int i = tid; i < total; i += 512) {
      uint2 e = entryAt(i);
      if ((e.x >> 20) == uB) {
        int mid = (int)((e.x >> 8) & 0xFFFu);
        if (mid > B2) { int p = atomicAdd(&sCnt, 1); ciL[p] = (int)e.y; ckL[p] = e.x; }
        else if (mid == B2) atomicAdd(&hist[e.x & 0xFFu], 1);
      }
    }
    __syncthreads();
    int needed3 = needed - cA2;
    int B3, cA3, t3;
    findThresholdBin(hist, 256, needed3, B3, cA3, t3, shWave, shOut);

    // ---- pass C: gather lo>B3; collect exact-threshold ties ----
    for (int i = tid; i < total; i += 512) {
      uint2 e = entryAt(i);
      if ((e.x >> 20) == uB && (int)((e.x >> 8) & 0xFFFu) == B2) {
        int lo = (int)(e.x & 0xFFu);
        if (lo > B3) { int p = atomicAdd(&sCnt, 1); ciL[p] = (int)e.y; ckL[p] = e.x; }
        else if (lo == B3) { int p = atomicAdd(&sTie, 1); if (p < 256) eqI[p] = (int)e.y; }
      }
    }
    __syncthreads();
    int needed4 = needed3 - cA3;   // >= 1; slots [0, kM-needed4) now filled
    unsigned exactKey = (uB << 20) | ((unsigned)B2 << 8) | (unsigned)B3;
    int ties = sTie;
    if (ties == needed4) {
      // typical: exact-threshold key unique (or exactly fills) -> direct append
      if (tid < needed4) { ciL[kM - needed4 + tid] = eqI[tid]; ckL[kM - needed4 + tid] = exactKey; }
    } else if (tid == 0) {
      // rare: surplus exact-key ties -> smallest original indices win (reference order)
      int base0 = kM - needed4; int lastI = -1;
      for (int q = 0; q < needed4; ++q) {
        int mv = INT_MAX;
        for (int i = 0; i < total; ++i) {
          uint2 e = entryAt(i);
          if (e.x == exactKey) { int ix = (int)e.y; if (ix > lastI && ix < mv) mv = ix; }
        }
        ciL[base0 + q] = mv; ckL[base0 + q] = exactKey; lastI = mv;
      }
    }
    __syncthreads();
  }

  // ================= NMS phase: wave 0 only, 4 candidates/lane, register state =========
  if (tid >= 64) return;
  int lane = tid;

  float x1[4], y1[4], x2[4], y2[4], val[4], s[4];
  int cls[4];
  bool kept[4];

  #pragma unroll
  for (int q = 0; q < 4; ++q) {
    int slot = q * 64 + lane;
    int n = ciL[slot];
    float sc = key_to_score(ckL[slot]);  // bit-exact score from kernel 1 (kNEG for filler)
    kept[q] = false;
    x1[q] = y1[q] = x2[q] = y2[q] = 0.f;
    cls[q] = 0; val[q] = sc; s[q] = sc;
    if (n >= 0) {
      int lvl, a, gi, gj; float stride;
      const float* p = cell_ptr(p0, p1, p2, b, n, lvl, a, gi, gj, stride);
      const float2* r2 = (const float2*)p;   // rows are 104 B: even-float offsets 8B-aligned
      float2 c01 = r2[0], c23 = r2[1];
      float cx = (fsigm(c01.x) + (float)gj) * stride;
      float cy = (fsigm(c01.y) + (float)gi) * stride;
      float w = fexpf(c23.x) * c_anchors[lvl][a][0];  // (exp*anc/stride)*stride == exp*anc
      float h = fexpf(c23.y) * c_anchors[lvl][a][1];
      x1[q] = fminf(fmaxf(cx - 0.5f * w, 0.f), 608.f);
      y1[q] = fminf(fmaxf(cy - 0.5f * h, 0.f), 608.f);
      x2[q] = fminf(fmaxf(cx + 0.5f * w, 0.f), 608.f);
      y2[q] = fminf(fmaxf(cy + 0.5f * h, 0.f), 608.f);
      float lm = -3.4e38f; int mc = 0;
      #pragma unroll
      for (int j = 3; j < 13; ++j) {
        float2 v = r2[j];
        int c0 = 2 * (j - 3);
        if (v.x > lm) { lm = v.x; mc = c0; }
        if (v.y > lm) { lm = v.y; mc = c0 + 1; }
      }
      cls[q] = mc;
    }
  }

  // top-8 kept ORIGINAL scores, maintained identically (uniformly) on all lanes
  float top8[8];
  #pragma unroll
  for (int i = 0; i < 8; ++i) top8[i] = kNEG;
  int keptCount = 0;

  for (int it = 0; it < kM; ++it) {
    float bv = s[0]; int bq = 0;
    #pragma unroll
    for (int q = 1; q < 4; ++q) if (s[q] > bv) { bv = s[q]; bq = q; }
    int bi = bq * 64 + lane;
    waveArgmax(bv, bi);
    if (bv < 0.1f) break;   // all remaining reference steps are no-ops -> exact

    int wlane = bi & 63, wq = bi >> 6;
    float jx1 = __shfl(sel4f(x1, wq), wlane);
    float jy1 = __shfl(sel4f(y1, wq), wlane);
    float jx2 = __shfl(sel4f(x2, wq), wlane);
    float jy2 = __shfl(sel4f(y2, wq), wlane);
    float jval = __shfl(sel4f(val, wq), wlane);
    int   cj  = __shfl(sel4i(cls, wq), wlane);

    float a1 = (jx2 - jx1 + 1.0f) * (jy2 - jy1 + 1.0f);
    #pragma unroll
    for (int q = 0; q < 4; ++q) {
      if (cls[q] == cj) {
        float ix1 = fmaxf(jx1, x1[q]), iy1 = fmaxf(jy1, y1[q]);
        float ix2 = fminf(jx2, x2[q]), iy2 = fminf(jy2, y2[q]);
        float inter = fmaxf(ix2 - ix1 + 1.0f, 0.0f) * fmaxf(iy2 - iy1 + 1.0f, 0.0f);
        float a2 = (x2[q] - x1[q] + 1.0f) * (y2[q] - y1[q] + 1.0f);
        float iou = inter / (a1 + a2 - inter + 1e-16f);
        s[q] *= fexpf(-(iou * iou) * 2.0f);
      }
      if (bi == q * 64 + lane) { kept[q] = true; s[q] = kNEG; }  // winner slot
    }

    // early-stop bookkeeping (uniform scalar work on every lane)
    float v = jval;
    #pragma unroll
    for (int i = 0; i < 8; ++i) { float m = fmaxf(top8[i], v); v = fminf(top8[i], v); top8[i] = m; }
    ++keptCount;
    if (keptCount >= kTopK) {
      float am = kNEG;
      #pragma unroll
      for (int q = 0; q < 4; ++q) if (s[q] >= 0.1f) am = fmaxf(am, val[q]);
      am = waveMax(am);
      // no alive candidate's ORIGINAL score can beat the 8th-best kept original:
      // s is monotone non-increasing, originals fixed, kept flags never revert -> exact stop
      if (am < top8[7]) break;
    }
  }

  // keep_top_k by ORIGINAL score among kept
  float f[4];
  #pragma unroll
  for (int q = 0; q < 4; ++q) f[q] = kept[q] ? val[q] : kNEG;
  for (int k = 0; k < kTopK; ++k) {
    float bv = f[0]; int bq = 0;
    #pragma unroll
    for (int q = 1; q < 4; ++q) if (f[q] > bv) { bv = f[q]; bq = q; }
    int bi = bq * 64 + lane;
    waveArgmax(bv, bi);
    int wlane = bi & 63, wq = bi >> 6;
    if (lane == wlane) {
      float* o = out + (size_t)(b * kTopK + k) * 6;
      if (bv > kNEG * 0.5f) {
        o[0] = sel4f(x1, wq); o[1] = sel4f(y1, wq);
        o[2] = sel4f(x2, wq); o[3] = sel4f(y2, wq);
        o[4] = sel4f(val, wq); o[5] = (float)sel4i(cls, wq);
      } else {
        o[0] = 0.f; o[1] = 0.f; o[2] = 0.f; o[3] = 0.f; o[4] = 0.f; o[5] = 0.f;
      }
    }
    #pragma unroll
    for (int q = 0; q < 4; ++q) if (bi == q * 64 + lane) f[q] = kNEG;
  }
}

// ---------------- host launch ----------------
extern "C" void kernel_launch(void* const* d_in, const int* in_sizes, int n_in,
                              void* d_out, int out_size, void* d_ws, size_t ws_size,
                              hipStream_t stream) {
  const float* p0 = (const float*)d_in[0];
  const float* p1 = (const float*)d_in[1];
  const float* p2 = (const float*)d_in[2];
  float* out = (float*)d_out;

  // workspace layout:
  //   list uint2[kB*90*256]  11.80 MB  per-tile compacted (key, index) candidate pairs
  //   tcnt int[kB*90]        23 KB     per-tile candidate counts (always fully written)
  uint2* list = (uint2*)d_ws;
  int* tcnt = (int*)((char*)d_ws + (size_t)kB * kTilesPerImg * 256 * sizeof(uint2));

  score_kernel<<<kGridScore, 256, 0, stream>>>(p0, p1, p2, list, tcnt);
  select_nms_kernel<<<kB, 512, 0, stream>>>(list, tcnt, p0, p1, p2, out);
}